// Round 11
// baseline (325.606 us; speedup 1.0000x reference)
//
#include <hip/hip_runtime.h>

// SNN policy, dense-MFMA edition (round 16: 8-wave block, 1 tile/wave).
// Block = 8 waves = 512 threads, 16 batch elements. Wave w owns neuron
// tile [16w, 16w+16) -> per-wave weights halve (BrecHi/Mi[4] = 32 AGPR),
// which breaks the register wall that pinned occupancy at 3 waves/SIMD:
// __launch_bounds__(512,4) -> 128 regs/wave, 2 blocks/CU = 4 waves/SIMD.
// Per-wave MFMA per step halves (9 vs 18) -> shorter serial chains per
// barrier interval + one extra covering wave. Total work unchanged.
// Bwout lives in LDS (built by wave 0; read 4x b128/step by des wave
// only). Spike masks precomputed by wave 1 (r15 technique). z spikes:
// 16x128 bf16 LDS tile (swizzled, double-buffered), 1 barrier/step.
// All per-element op chains bit-identical to r15 -> absmax 0.001953125.
// Guard: WRITE_SIZE == 512 KB (spill tripwire; spill -> revert to r15).

#pragma clang fp contract(off)

typedef float f32x4 __attribute__((ext_vector_type(4)));
typedef float f32x2 __attribute__((ext_vector_type(2)));
typedef short short8 __attribute__((ext_vector_type(8)));
typedef int int4v __attribute__((ext_vector_type(4)));

constexpr int TSTEPS = 40;

// round-to-nearest-even bf16, returned as f32 bit pattern (low 16 zero)
__device__ __forceinline__ unsigned rnbf(float f) {
    unsigned u = __float_as_uint(f);
    return (u + 0x7FFFu + ((u >> 16) & 1u)) & 0xFFFF0000u;
}

// 2-way RN split of an f32 pair into packed bf16 (lo16 = even-k element)
__device__ __forceinline__ void split2pair(float a, float b,
                                           unsigned& hi, unsigned& mi) {
    unsigned ha = rnbf(a), hb = rnbf(b);
    float ra = a - __uint_as_float(ha);
    float rb = b - __uint_as_float(hb);
    unsigned ma = rnbf(ra), mb = rnbf(rb);
    hi = (ha >> 16) | (hb & 0xFFFF0000u);
    mi = (ma >> 16) | (mb & 0xFFFF0000u);
}

__device__ __forceinline__ f32x4 mfma16(int4v a, int4v b, f32x4 c) {
    return __builtin_amdgcn_mfma_f32_16x16x32_bf16(
        __builtin_bit_cast(short8, a), __builtin_bit_cast(short8, b), c, 0, 0, 0);
}

template <int CTRL>
__device__ __forceinline__ float dpp_mov(float v) {
    return __int_as_float(
        __builtin_amdgcn_update_dpp(0, __float_as_int(v), CTRL, 0xF, 0xF, true));
}

__device__ __forceinline__ f32x2 lo2(f32x4 a) {
    return __builtin_shufflevector(a, a, 0, 1);
}
__device__ __forceinline__ f32x2 hi2(f32x4 a) {
    return __builtin_shufflevector(a, a, 2, 3);
}

__global__ __launch_bounds__(512, 4) void snn_kernel(
    const float* __restrict__ x,
    const float* __restrict__ w_in,
    const float* __restrict__ w_rec,
    const float* __restrict__ w_out,
    float* __restrict__ out)
{
    __shared__ char zraw[8192];      // 2 x (16 rows x 128 cols bf16), swizzled
    __shared__ char woutlds[4096];   // Bwout frags: [kc][lane] 16B
    __shared__ __align__(16) unsigned long long msk[TSTEPS][2];  // spike masks

    const int tid = threadIdx.x;
    const int l   = tid & 63;
    const int wv  = tid >> 6;      // wave 0..7
    const int cl  = l & 15;        // row (A/write col-lane) / col (B/C)
    const int kg  = l >> 4;        // k-group 0..3
    const int kb  = kg * 8;        // k base within a 32-chunk
    const int b0  = blockIdx.x * 16;
    const int n   = wv * 16 + cl;  // this wave's neuron column
    const int des = blockIdx.x & 7; // designated readout wave

    // packed-op constants
    const f32x2 P1  = {0.1f, 0.1f};
    const f32x2 P02 = {0.2f, 0.2f};

    // ---- recurrent weights for this wave's 16 neurons: both splits -> regs
    int4v BrecHi[4], BrecMi[4];
#pragma unroll
    for (int kc = 0; kc < 4; ++kc) {
        const float* wp = w_rec + n * 128 + kc * 32 + kb;
        float4 wa = *reinterpret_cast<const float4*>(wp);
        float4 wb = *reinterpret_cast<const float4*>(wp + 4);
        float w8[8] = {wa.x, wa.y, wa.z, wa.w, wb.x, wb.y, wb.z, wb.w};
#pragma unroll
        for (int r = 0; r < 4; ++r) {
            unsigned h, m;
            split2pair(w8[2 * r], w8[2 * r + 1], h, m);
            BrecHi[kc][r] = (int)h;
            BrecMi[kc][r] = (int)m;
        }
    }

    // ---- input weights, hi+mid PACKED in one B-frag (kg0=hi, kg1=mid)
    int4v BwinPk;
    {
        float w8[8];
#pragma unroll
        for (int j = 0; j < 8; ++j)
            w8[j] = (kg < 2) ? w_in[n * 8 + j] : 0.0f;
#pragma unroll
        for (int r = 0; r < 4; ++r) {
            unsigned h, m;
            split2pair(w8[2 * r], w8[2 * r + 1], h, m);
            BwinPk[r] = (int)(kg == 0 ? h : (kg == 1 ? m : 0u));
        }
    }

    // ---- readout weights -> LDS frags (wave 0):
    // cols 0,1 = hi(ch0),hi(ch1); cols 2,3 = mid
    if (wv == 0) {
        int  ch   = cl & 1;
        int  part = (cl >> 1) & 1;
        bool act  = cl < 4;
#pragma unroll
        for (int kc = 0; kc < 4; ++kc) {
            float w8[8];
#pragma unroll
            for (int j = 0; j < 8; ++j)
                w8[j] = act ? w_out[ch * 128 + kc * 32 + kb + j] : 0.0f;
            int4v f;
#pragma unroll
            for (int r = 0; r < 4; ++r) {
                unsigned h, m;
                split2pair(w8[2 * r], w8[2 * r + 1], h, m);
                f[r] = (int)(part ? m : h);
            }
            *reinterpret_cast<int4v*>(&woutlds[kc * 1024 + l * 16]) = f;
        }
    }

    // ---- encoder: PRECOMPUTE all 40 spike masks (wave 1; r15 technique)
    if (wv == 1) {
        float xv0 = x[(size_t)(b0 + (l >> 3)) * 4 + (l & 3)];
        float xv1 = x[(size_t)(b0 + 8 + (l >> 3)) * 4 + (l & 3)];
        float s0 = 50.0f * xv0, s1 = 50.0f * xv1;
        f32x2 cur, ve = {0.0f, 0.0f};
        cur[0] = (l & 4) ? fmaxf(-s0, 0.0f) : fmaxf(s0, 0.0f);
        cur[1] = (l & 4) ? fmaxf(-s1, 0.0f) : fmaxf(s1, 0.0f);
#pragma unroll 1
        for (int u = 0; u < TSTEPS; ++u) {
            f32x2 te = cur - ve;            // (0-ve)+cur == cur-ve
            f32x2 vv = ve + P1 * te;
            bool e0 = vv[0] > 1.0f, e1 = vv[1] > 1.0f;
            unsigned long long bm0 = __ballot(e0), bm1 = __ballot(e1);
            ve[0] = e0 ? 0.0f : vv[0];
            ve[1] = e1 ? 0.0f : vv[1];
            if (l == 0) { msk[u][0] = bm0; msk[u][1] = bm1; }
        }
    }

    // ---- states (single tile; C-frag layout: col=lane&15, row=(lane>>4)*4+reg)
    f32x2 iSl = {0,0}, iSh = {0,0}, vSl = {0,0}, vSh = {0,0};
    f32x2 io_l = {0,0}, io_h = {0,0}, vo_l = {0,0}, vo_h = {0,0};
    f32x4 mx = {-3e38f,-3e38f,-3e38f,-3e38f};

    // ---- z-tile LDS addresses (byte ^ ((row&7)<<4) swizzle; bit12 = buffer)
    // write addr(r) = (awrb ^ (r<<4)) + r*256   [r compile-time]
    unsigned awrb = (unsigned)((kg * 1024 + n * 2) ^ ((kg & 1) << 6));
    unsigned ard  = (unsigned)((cl * 256 + kg * 16) ^ ((cl & 7) << 4)) | 4096u;

    auto loadfrags = [&](int4v* zf) {
#pragma unroll
        for (int kc = 0; kc < 4; ++kc)
            zf[kc] = *reinterpret_cast<int4v*>(&zraw[ard ^ (unsigned)(kc << 6)]);
    };

    auto readout = [&](const int4v* zf) {
        int4v bw[4];
#pragma unroll
        for (int kc = 0; kc < 4; ++kc)
            bw[kc] = *reinterpret_cast<int4v*>(&woutlds[kc * 1024 + l * 16]);
        f32x4 cro = {0,0,0,0};
#pragma unroll
        for (int kc = 0; kc < 4; ++kc) cro = mfma16(zf[kc], bw[kc], cro);
        f32x4 cr;
#pragma unroll
        for (int r = 0; r < 4; ++r) cr[r] = cro[r] + dpp_mov<0x4E>(cro[r]);
        // von = vo + 0.1*((0 - vo) + io); (0-vo)+io == io - vo (one rounding)
        f32x2 t2l = io_l - vo_l;
        f32x2 t2h = io_h - vo_h;
        f32x2 vnl = vo_l + P1 * t2l;
        f32x2 vnh = vo_h + P1 * t2h;
        // io = (io - 0.2*io) + cr   (vo used OLD io above)
        io_l = (io_l - P02 * io_l) + lo2(cr);
        io_h = (io_h - P02 * io_h) + hi2(cr);
        vo_l = vnl;
        vo_h = vnh;
        mx[0] = fmaxf(mx[0], vnl[0]);
        mx[1] = fmaxf(mx[1], vnl[1]);
        mx[2] = fmaxf(mx[2], vnh[0]);
        mx[3] = fmaxf(mx[3], vnh[1]);
    };

    auto encoder_lif = [&](int u, bool with_rec, const int4v* zf) {
        // spike byte from precomputed masks (uniform LDS read)
        unsigned long long bm0 = msk[u][0];
        unsigned long long bm1 = msk[u][1];
        unsigned long long src = (cl < 8) ? (bm0 >> (cl * 8)) : (bm1 >> ((cl - 8) * 8));
        unsigned byt = (l < 32) ? ((unsigned)src & 0xFFu) : 0u;
        int4v axt;
        axt[0] = (int)(((byt & 1u)   ? 0x3F80u : 0u) | ((byt & 2u)   ? 0x3F800000u : 0u));
        axt[1] = (int)(((byt & 4u)   ? 0x3F80u : 0u) | ((byt & 8u)   ? 0x3F800000u : 0u));
        axt[2] = (int)(((byt & 16u)  ? 0x3F80u : 0u) | ((byt & 32u)  ? 0x3F800000u : 0u));
        axt[3] = (int)(((byt & 64u)  ? 0x3F80u : 0u) | ((byt & 128u) ? 0x3F800000u : 0u));
        f32x4 cin = {0,0,0,0};
        cin = mfma16(axt, BwinPk, cin);      // hi + mid in one pass
        f32x4 crec = {0,0,0,0};
        if (with_rec) {
#pragma unroll
            for (int kc = 0; kc < 4; ++kc)
                crec = mfma16(zf[kc], BrecMi[kc], crec);
#pragma unroll
            for (int kc = 0; kc < 4; ++kc)
                crec = mfma16(zf[kc], BrecHi[kc], crec);
        }
        // id = i - 0.2*i ; tt = (0-v)+i == i-v ; vd = v + 0.1*tt
        f32x2 idl = iSl - P02 * iSl;
        f32x2 idh = iSh - P02 * iSh;
        f32x2 ttl = iSl - vSl;
        f32x2 tth = iSh - vSh;
        f32x2 vdl = vSl + P1 * ttl;
        f32x2 vdh = vSh + P1 * tth;
#pragma unroll
        for (int r = 0; r < 4; ++r) {
            float vdr = (r < 2) ? vdl[r] : vdh[r - 2];
            bool zb = vdr > 1.0f;
            float vres = zb ? 0.0f : vdr;
            if (r == 0)      vSl[0] = vres;
            else if (r == 1) vSl[1] = vres;
            else if (r == 2) vSh[0] = vres;
            else             vSh[1] = vres;
            short zv = zb ? (short)0x3F80 : (short)0;
            unsigned a = (awrb ^ (unsigned)(r << 4)) + (unsigned)(r * 256);
            *reinterpret_cast<short*>(&zraw[a]) = zv;
        }
        // iS = (id + cin) + crec    [r11 order]
        iSl = (idl + lo2(cin)) + lo2(crec);
        iSh = (idh + hi2(cin)) + hi2(crec);
    };

    auto toggle = [&]() {
        ard  ^= 4096u;
        awrb ^= 4096u;
    };

    // ---- prologue: masks + Bwout visible -> z(0) written -> z(0) visible
    __syncthreads();
    encoder_lif(0, false, nullptr);
    __syncthreads();
    toggle();

#pragma unroll 1
    for (int u = 1; u < TSTEPS; ++u) {
        int4v zf[4];
        loadfrags(zf);                     // z(u-1)
        if (wv == des) readout(zf);        // vo(u-1), io(u-1): one wave only
        encoder_lif(u, true, zf);          // i/v/z(u)
        __syncthreads();
        toggle();
    }

    // ---- epilogue: vo(39) from z(39); softmax + store (designated wave)
    if (wv == des) {
        int4v zf[4];
        loadfrags(zf);
        readout(zf);
#pragma unroll
        for (int r = 0; r < 4; ++r) {
            float partner = dpp_mov<0xB1>(mx[r]);
            float mm = fmaxf(mx[r], partner);
            float es = expf(mx[r] - mm);
            float ep = expf(partner - mm);
            float inv = 1.0f / (es + ep);
            float pr = es * inv;
            if (cl < 2) out[(size_t)(b0 + kg * 4 + r) * 2 + cl] = pr;
        }
    }
}

extern "C" void kernel_launch(void* const* d_in, const int* in_sizes, int n_in,
                              void* d_out, int out_size, void* d_ws, size_t ws_size,
                              hipStream_t stream) {
    const float* x     = (const float*)d_in[0];
    const float* w_in  = (const float*)d_in[1];
    const float* w_rec = (const float*)d_in[2];
    const float* w_out = (const float*)d_in[3];
    float* out = (float*)d_out;

    int B = in_sizes[0] / 4;      // x is (B, 4)
    int blocks = B / 16;          // 16 batch elements per 512-thread block
    snn_kernel<<<blocks, 512, 0, stream>>>(x, w_in, w_rec, w_out, out);
}

// Round 12
// 240.749 us; speedup vs baseline: 1.3525x; 1.3525x over previous
//
#include <hip/hip_runtime.h>

// SNN policy, dense-MFMA edition (round 17: r15 + axt table + rotating
// deferred readout). Block = 4 waves = 16 batch (r16's 8-wave variant
// REVERTED: +33% occupancy but 2x bank conflicts + bigger barrier convoy
// = 354us). Wave w owns neurons [32w,32w+32); both w_rec splits in regs.
//
// r17 changes (theory: des-wave straggler + redundant per-step VALU):
//  1. axt A-frags for all 40 steps precomputed into a 20KB LDS table by
//     one wave; per step each wave does ONE ds_read_b128 instead of
//     mask-read + ~18 insts of frag build. Lanes>=32 read (l&31)'s frag:
//     BwinPk is exactly 0 for kg>=2 and spike frags are finite -> A*0=0.
//  2. Readout rotates across waves (wv == u&3) and is DEFERRED: in-loop
//     only 4 MFMA + dpp + 128B cr-store; the LI recurrence (io/vo/mx)
//     replays in the epilogue on one wave from the 40 stored cr values.
//     cr is a pure function of z; LI chain ops/order identical to r15.
// Guard: WRITE_SIZE == 512 KB, VGPR <= 84 (spill -> revert to r15).

#pragma clang fp contract(off)

typedef float f32x4 __attribute__((ext_vector_type(4)));
typedef float f32x2 __attribute__((ext_vector_type(2)));
typedef short short8 __attribute__((ext_vector_type(8)));
typedef int int4v __attribute__((ext_vector_type(4)));

constexpr int TSTEPS = 40;

// round-to-nearest-even bf16, returned as f32 bit pattern (low 16 zero)
__device__ __forceinline__ unsigned rnbf(float f) {
    unsigned u = __float_as_uint(f);
    return (u + 0x7FFFu + ((u >> 16) & 1u)) & 0xFFFF0000u;
}

// 2-way RN split of an f32 pair into packed bf16 (lo16 = even-k element)
__device__ __forceinline__ void split2pair(float a, float b,
                                           unsigned& hi, unsigned& mi) {
    unsigned ha = rnbf(a), hb = rnbf(b);
    float ra = a - __uint_as_float(ha);
    float rb = b - __uint_as_float(hb);
    unsigned ma = rnbf(ra), mb = rnbf(rb);
    hi = (ha >> 16) | (hb & 0xFFFF0000u);
    mi = (ma >> 16) | (mb & 0xFFFF0000u);
}

__device__ __forceinline__ f32x4 mfma16(int4v a, int4v b, f32x4 c) {
    return __builtin_amdgcn_mfma_f32_16x16x32_bf16(
        __builtin_bit_cast(short8, a), __builtin_bit_cast(short8, b), c, 0, 0, 0);
}

template <int CTRL>
__device__ __forceinline__ float dpp_mov(float v) {
    return __int_as_float(
        __builtin_amdgcn_update_dpp(0, __float_as_int(v), CTRL, 0xF, 0xF, true));
}

__device__ __forceinline__ f32x2 lo2(f32x4 a) {
    return __builtin_shufflevector(a, a, 0, 1);
}
__device__ __forceinline__ f32x2 hi2(f32x4 a) {
    return __builtin_shufflevector(a, a, 2, 3);
}

__global__ __launch_bounds__(256, 3) void snn_kernel(
    const float* __restrict__ x,
    const float* __restrict__ w_in,
    const float* __restrict__ w_rec,
    const float* __restrict__ w_out,
    float* __restrict__ out)
{
    __shared__ __align__(16) char zraw[8192];   // 2 x (16x128 bf16), swizzled
    __shared__ __align__(16) char axtlds[TSTEPS * 512];  // 20480: axt frags
    __shared__ float crlds[TSTEPS][16][2];      // 5120: cr(u)[batchrow][ch]

    const int tid = threadIdx.x;
    const int l   = tid & 63;
    const int wv  = tid >> 6;      // wave 0..3
    const int cl  = l & 15;        // row (A/write col-lane) / col (B/C)
    const int kg  = l >> 4;        // k-group 0..3
    const int kb  = kg * 8;        // k base within a 32-chunk
    const int b0  = blockIdx.x * 16;
    const int Ns  = wv * 32;       // neuron slice base
    const int des = blockIdx.x & 3; // builder / epilogue wave

    // packed-op constants
    const f32x2 P1  = {0.1f, 0.1f};
    const f32x2 P02 = {0.2f, 0.2f};

    // ---- recurrent weights: BOTH splits -> registers (r11/r15 layout)
    int4v BrecHi[2][4], BrecMi[2][4];
#pragma unroll
    for (int t = 0; t < 2; ++t) {
        int n = Ns + t * 16 + cl;
#pragma unroll
        for (int kc = 0; kc < 4; ++kc) {
            const float* wp = w_rec + n * 128 + kc * 32 + kb;
            float4 wa = *reinterpret_cast<const float4*>(wp);
            float4 wb = *reinterpret_cast<const float4*>(wp + 4);
            float w8[8] = {wa.x, wa.y, wa.z, wa.w, wb.x, wb.y, wb.z, wb.w};
#pragma unroll
            for (int r = 0; r < 4; ++r) {
                unsigned h, m;
                split2pair(w8[2 * r], w8[2 * r + 1], h, m);
                BrecHi[t][kc][r] = (int)h;
                BrecMi[t][kc][r] = (int)m;
            }
        }
    }

    // ---- input weights, hi+mid PACKED in one B-frag (kg0=hi, kg1=mid)
    int4v BwinPk[2];
#pragma unroll
    for (int t = 0; t < 2; ++t) {
        int n = Ns + t * 16 + cl;
        float w8[8];
#pragma unroll
        for (int j = 0; j < 8; ++j)
            w8[j] = (kg < 2) ? w_in[n * 8 + j] : 0.0f;
#pragma unroll
        for (int r = 0; r < 4; ++r) {
            unsigned h, m;
            split2pair(w8[2 * r], w8[2 * r + 1], h, m);
            BwinPk[t][r] = (int)(kg == 0 ? h : (kg == 1 ? m : 0u));
        }
    }

    // ---- readout weights: cols 0,1 = hi(ch0),hi(ch1); cols 2,3 = mid
    int4v Bwout[4];
    {
        int  ch   = cl & 1;
        int  part = (cl >> 1) & 1;
        bool act  = cl < 4;
#pragma unroll
        for (int kc = 0; kc < 4; ++kc) {
            float w8[8];
#pragma unroll
            for (int j = 0; j < 8; ++j)
                w8[j] = act ? w_out[ch * 128 + kc * 32 + kb + j] : 0.0f;
#pragma unroll
            for (int r = 0; r < 4; ++r) {
                unsigned h, m;
                split2pair(w8[2 * r], w8[2 * r + 1], h, m);
                Bwout[kc][r] = (int)(part ? m : h);
            }
        }
    }

    // ---- encoder: PRECOMPUTE all 40 axt A-frags (wave des). Same op
    // chain as r15's per-step encoder, hoisted; frag build done once.
    if (wv == des) {
        float xv0 = x[(size_t)(b0 + (l >> 3)) * 4 + (l & 3)];
        float xv1 = x[(size_t)(b0 + 8 + (l >> 3)) * 4 + (l & 3)];
        float s0 = 50.0f * xv0, s1 = 50.0f * xv1;
        f32x2 cur, ve = {0.0f, 0.0f};
        cur[0] = (l & 4) ? fmaxf(-s0, 0.0f) : fmaxf(s0, 0.0f);
        cur[1] = (l & 4) ? fmaxf(-s1, 0.0f) : fmaxf(s1, 0.0f);
#pragma unroll 1
        for (int u = 0; u < TSTEPS; ++u) {
            f32x2 te = cur - ve;            // (0-ve)+cur == cur-ve
            f32x2 vv = ve + P1 * te;
            bool e0 = vv[0] > 1.0f, e1 = vv[1] > 1.0f;
            unsigned long long bm0 = __ballot(e0), bm1 = __ballot(e1);
            ve[0] = e0 ? 0.0f : vv[0];
            ve[1] = e1 ? 0.0f : vv[1];
            unsigned long long src = (cl < 8) ? (bm0 >> (cl * 8))
                                              : (bm1 >> ((cl - 8) * 8));
            unsigned byt = (unsigned)src & 0xFFu;
            int4v axt;
            axt[0] = (int)(((byt & 1u)   ? 0x3F80u : 0u) | ((byt & 2u)   ? 0x3F800000u : 0u));
            axt[1] = (int)(((byt & 4u)   ? 0x3F80u : 0u) | ((byt & 8u)   ? 0x3F800000u : 0u));
            axt[2] = (int)(((byt & 16u)  ? 0x3F80u : 0u) | ((byt & 32u)  ? 0x3F800000u : 0u));
            axt[3] = (int)(((byt & 64u)  ? 0x3F80u : 0u) | ((byt & 128u) ? 0x3F800000u : 0u));
            if (l < 32)
                *reinterpret_cast<int4v*>(&axtlds[u * 512 + l * 16]) = axt;
        }
    }

    // ---- states (C-frag layout: col=lane&15, row=(lane>>4)*4+reg)
    f32x2 iSl[2] = {{0,0},{0,0}}, iSh[2] = {{0,0},{0,0}};
    f32x2 vSl[2] = {{0,0},{0,0}}, vSh[2] = {{0,0},{0,0}};

    // ---- z-tile LDS addresses (byte ^ ((row&7)<<4) swizzle; bit12 = buffer)
    unsigned awrb[2];
#pragma unroll
    for (int t = 0; t < 2; ++t) {
        int col = Ns + t * 16 + cl;
        awrb[t] = (unsigned)((kg * 1024 + col * 2) ^ ((kg & 1) << 6));
    }
    unsigned ard = (unsigned)((cl * 256 + kg * 16) ^ ((cl & 7) << 4)) | 4096u;

    auto loadfrags = [&](int4v* zf) {
#pragma unroll
        for (int kc = 0; kc < 4; ++kc)
            zf[kc] = *reinterpret_cast<int4v*>(&zraw[ard ^ (unsigned)(kc << 6)]);
    };

    // readout MFMA only; cr stored to LDS slot (LI recurrence deferred)
    auto readout_cr = [&](const int4v* zf, int slot) {
        f32x4 cro = {0,0,0,0};
#pragma unroll
        for (int kc = 0; kc < 4; ++kc) cro = mfma16(zf[kc], Bwout[kc], cro);
        f32x4 cr;
#pragma unroll
        for (int r = 0; r < 4; ++r) cr[r] = cro[r] + dpp_mov<0x4E>(cro[r]);
        if (cl < 2) {
#pragma unroll
            for (int r = 0; r < 4; ++r) crlds[slot][kg * 4 + r][cl] = cr[r];
        }
    };

    auto encoder_lif = [&](int u, bool with_rec, const int4v* zf) {
        int4v axt = *reinterpret_cast<const int4v*>(
            &axtlds[u * 512 + (l & 31) * 16]);
#pragma unroll
        for (int t = 0; t < 2; ++t) {
            f32x4 cin = {0,0,0,0};
            cin = mfma16(axt, BwinPk[t], cin);   // hi + mid in one pass
            f32x4 crec = {0,0,0,0};
            if (with_rec) {
#pragma unroll
                for (int kc = 0; kc < 4; ++kc)
                    crec = mfma16(zf[kc], BrecMi[t][kc], crec);
#pragma unroll
                for (int kc = 0; kc < 4; ++kc)
                    crec = mfma16(zf[kc], BrecHi[t][kc], crec);
            }
            // id = i - 0.2*i ; tt = (0-v)+i == i-v ; vd = v + 0.1*tt
            f32x2 idl = iSl[t] - P02 * iSl[t];
            f32x2 idh = iSh[t] - P02 * iSh[t];
            f32x2 ttl = iSl[t] - vSl[t];
            f32x2 tth = iSh[t] - vSh[t];
            f32x2 vdl = vSl[t] + P1 * ttl;
            f32x2 vdh = vSh[t] + P1 * tth;
#pragma unroll
            for (int r = 0; r < 4; ++r) {
                float vdr = (r < 2) ? vdl[r] : vdh[r - 2];
                bool zb = vdr > 1.0f;
                float vres = zb ? 0.0f : vdr;
                if (r == 0)      vSl[t][0] = vres;
                else if (r == 1) vSl[t][1] = vres;
                else if (r == 2) vSh[t][0] = vres;
                else             vSh[t][1] = vres;
                short zv = zb ? (short)0x3F80 : (short)0;
                unsigned a = (awrb[t] ^ (unsigned)(r << 4)) + (unsigned)(r * 256);
                *reinterpret_cast<short*>(&zraw[a]) = zv;
            }
            // iS = (id + cin) + crec    [r11/r15 order]
            iSl[t] = (idl + lo2(cin)) + lo2(crec);
            iSh[t] = (idh + hi2(cin)) + hi2(crec);
        }
    };

    auto toggle = [&]() {
        ard ^= 4096u;
        awrb[0] ^= 4096u;
        awrb[1] ^= 4096u;
    };

    // ---- prologue: axt table visible -> z(0) written -> z(0) visible
    __syncthreads();
    encoder_lif(0, false, nullptr);
    __syncthreads();
    toggle();

#pragma unroll 1
    for (int u = 1; u < TSTEPS; ++u) {
        int4v zf[4];
        loadfrags(zf);                              // z(u-1)
        if (wv == (u & 3)) readout_cr(zf, u - 1);   // cr(u-1), one wave
        encoder_lif(u, true, zf);                   // i/v/z(u)
        __syncthreads();
        toggle();
    }

    // ---- epilogue (wave des): cr(39) from z(39), LI replay, softmax
    if (wv == des) {
        int4v zf[4];
        loadfrags(zf);
        readout_cr(zf, TSTEPS - 1);
        // replay: identical per-element op chain as r15's in-loop LI
        f32x4 io = {0,0,0,0}, vo = {0,0,0,0};
        f32x4 mx = {-3e38f,-3e38f,-3e38f,-3e38f};
        const int ch = cl & 1;
#pragma unroll 1
        for (int u = 0; u < TSTEPS; ++u) {
            f32x4 cr4;
#pragma unroll
            for (int r = 0; r < 4; ++r) cr4[r] = crlds[u][kg * 4 + r][ch];
            f32x4 vn;
#pragma unroll
            for (int r = 0; r < 4; ++r) {
                float t2 = io[r] - vo[r];           // (0-vo)+io == io-vo
                vn[r] = vo[r] + 0.1f * t2;
            }
#pragma unroll
            for (int r = 0; r < 4; ++r)
                io[r] = (io[r] - 0.2f * io[r]) + cr4[r];
            vo = vn;
#pragma unroll
            for (int r = 0; r < 4; ++r) mx[r] = fmaxf(mx[r], vn[r]);
        }
#pragma unroll
        for (int r = 0; r < 4; ++r) {
            float partner = dpp_mov<0xB1>(mx[r]);
            float mm = fmaxf(mx[r], partner);
            float es = expf(mx[r] - mm);
            float ep = expf(partner - mm);
            float inv = 1.0f / (es + ep);
            float pr = es * inv;
            if (cl < 2) out[(size_t)(b0 + kg * 4 + r) * 2 + cl] = pr;
        }
    }
}

extern "C" void kernel_launch(void* const* d_in, const int* in_sizes, int n_in,
                              void* d_out, int out_size, void* d_ws, size_t ws_size,
                              hipStream_t stream) {
    const float* x     = (const float*)d_in[0];
    const float* w_in  = (const float*)d_in[1];
    const float* w_rec = (const float*)d_in[2];
    const float* w_out = (const float*)d_in[3];
    float* out = (float*)d_out;

    int B = in_sizes[0] / 4;      // x is (B, 4)
    int blocks = B / 16;          // 16 batch elements per 256-thread block
    snn_kernel<<<blocks, 256, 0, stream>>>(x, w_in, w_rec, w_out, out);
}

// Round 13
// 220.622 us; speedup vs baseline: 1.4759x; 1.0912x over previous
//
#include <hip/hip_runtime.h>

// SNN policy, dense-MFMA edition (round 18: prep-kernel weight frags +
// wave-parallel axt build). Steady loop identical to r17 (271us rocprof,
// 240.7us bench): 4 waves, 16 batch, both w_rec splits in AGPR, axt
// A-frag table in LDS, rotating deferred readout, (256,3).
//
// r18 removes the two serial non-loop chunks (~10-12% of block lifetime):
//  1. Weight load+split (redundant across 4096 blocks) -> a prep kernel
//     writes all bf16-split frag images (recHi/recMi/winPk/wout, 76KB)
//     to d_ws once; main blocks do 22 coalesced b128 loads (L2-hot).
//  2. axt table build was one wave serial (~2600cy) while 3 waves waited.
//     Now ALL waves run the register-only ve recurrence (identical
//     ballots) and each builds/stores only u in [wv*10, wv*10+10).
// Frag values and all per-element op chains bit-identical to r17 ->
// absmax 0.001953125. Guard: WRITE_SIZE <= ~700KB (prep adds 76KB; any
// MB-scale balloon = spill = revert), VGPR <= 84.

#pragma clang fp contract(off)

typedef float f32x4 __attribute__((ext_vector_type(4)));
typedef float f32x2 __attribute__((ext_vector_type(2)));
typedef short short8 __attribute__((ext_vector_type(8)));
typedef int int4v __attribute__((ext_vector_type(4)));

constexpr int TSTEPS = 40;

// d_ws frag-image layout (units of int4v = 16B):
//   recHi : [  0..2047]  idx = (wv*8 + t*4 + kc)*64 + l
//   recMi : [2048..4095]  same indexing
//   winPk : [4096..4607]  idx = 4096 + (wv*2 + t)*64 + l
//   wout  : [4608..4863]  idx = 4608 + kc*64 + l
// total 4864 * 16B = 77824 bytes.

// round-to-nearest-even bf16, returned as f32 bit pattern (low 16 zero)
__device__ __forceinline__ unsigned rnbf(float f) {
    unsigned u = __float_as_uint(f);
    return (u + 0x7FFFu + ((u >> 16) & 1u)) & 0xFFFF0000u;
}

// 2-way RN split of an f32 pair into packed bf16 (lo16 = even-k element)
__device__ __forceinline__ void split2pair(float a, float b,
                                           unsigned& hi, unsigned& mi) {
    unsigned ha = rnbf(a), hb = rnbf(b);
    float ra = a - __uint_as_float(ha);
    float rb = b - __uint_as_float(hb);
    unsigned ma = rnbf(ra), mb = rnbf(rb);
    hi = (ha >> 16) | (hb & 0xFFFF0000u);
    mi = (ma >> 16) | (mb & 0xFFFF0000u);
}

__device__ __forceinline__ f32x4 mfma16(int4v a, int4v b, f32x4 c) {
    return __builtin_amdgcn_mfma_f32_16x16x32_bf16(
        __builtin_bit_cast(short8, a), __builtin_bit_cast(short8, b), c, 0, 0, 0);
}

template <int CTRL>
__device__ __forceinline__ float dpp_mov(float v) {
    return __int_as_float(
        __builtin_amdgcn_update_dpp(0, __float_as_int(v), CTRL, 0xF, 0xF, true));
}

__device__ __forceinline__ f32x2 lo2(f32x4 a) {
    return __builtin_shufflevector(a, a, 0, 1);
}
__device__ __forceinline__ f32x2 hi2(f32x4 a) {
    return __builtin_shufflevector(a, a, 2, 3);
}

// ---------------------------------------------------------------- prep
__global__ void prep_kernel(const float* __restrict__ w_in,
                            const float* __restrict__ w_rec,
                            const float* __restrict__ w_out,
                            int4v* __restrict__ ws)
{
    int gid = blockIdx.x * 256 + threadIdx.x;
    if (gid < 2048) {
        // recurrent frags: set = wv*8 + t*4 + kc
        int l = gid & 63, set = gid >> 6;
        int cl = l & 15, kg = l >> 4, kb = kg * 8;
        int wv = set >> 3, t = (set >> 2) & 1;
        int n = wv * 32 + t * 16 + cl;
        int kc = set & 3;
        const float* wp = w_rec + n * 128 + kc * 32 + kb;
        int4v hi, mi;
#pragma unroll
        for (int r = 0; r < 4; ++r) {
            unsigned h, m;
            split2pair(wp[2 * r], wp[2 * r + 1], h, m);
            hi[r] = (int)h;
            mi[r] = (int)m;
        }
        ws[set * 64 + l] = hi;
        ws[2048 + set * 64 + l] = mi;
    } else if (gid < 2560) {
        // input frags (hi+mid packed: kg0=hi, kg1=mid, kg2/3=0)
        int g = gid - 2048;
        int l = g & 63, set = g >> 6;     // set = wv*2 + t
        int cl = l & 15, kg = l >> 4;
        int wv = set >> 1, t = set & 1;
        int n = wv * 32 + t * 16 + cl;
        float w8[8];
#pragma unroll
        for (int j = 0; j < 8; ++j)
            w8[j] = (kg < 2) ? w_in[n * 8 + j] : 0.0f;
        int4v f;
#pragma unroll
        for (int r = 0; r < 4; ++r) {
            unsigned h, m;
            split2pair(w8[2 * r], w8[2 * r + 1], h, m);
            f[r] = (int)(kg == 0 ? h : (kg == 1 ? m : 0u));
        }
        ws[4096 + set * 64 + l] = f;
    } else if (gid < 2816) {
        // readout frags: cols 0,1 = hi(ch0),hi(ch1); cols 2,3 = mid
        int g = gid - 2560;
        int l = g & 63, kc = g >> 6;
        int cl = l & 15, kg = l >> 4, kb = kg * 8;
        int  ch   = cl & 1;
        int  part = (cl >> 1) & 1;
        bool act  = cl < 4;
        float w8[8];
#pragma unroll
        for (int j = 0; j < 8; ++j)
            w8[j] = act ? w_out[ch * 128 + kc * 32 + kb + j] : 0.0f;
        int4v f;
#pragma unroll
        for (int r = 0; r < 4; ++r) {
            unsigned h, m;
            split2pair(w8[2 * r], w8[2 * r + 1], h, m);
            f[r] = (int)(part ? m : h);
        }
        ws[4608 + kc * 64 + l] = f;
    }
}

// ---------------------------------------------------------------- main
__global__ __launch_bounds__(256, 3) void snn_kernel(
    const float* __restrict__ x,
    const int4v* __restrict__ ws,
    float* __restrict__ out)
{
    __shared__ __align__(16) char zraw[8192];   // 2 x (16x128 bf16), swizzled
    __shared__ __align__(16) char axtlds[TSTEPS * 512];  // 20480: axt frags
    __shared__ float crlds[TSTEPS][16][2];      // 5120: cr(u)[batchrow][ch]

    const int tid = threadIdx.x;
    const int l   = tid & 63;
    const int wv  = tid >> 6;      // wave 0..3
    const int cl  = l & 15;        // row (A/write col-lane) / col (B/C)
    const int kg  = l >> 4;        // k-group 0..3
    const int b0  = blockIdx.x * 16;
    const int Ns  = wv * 32;       // neuron slice base
    const int des = blockIdx.x & 3; // epilogue wave

    // packed-op constants
    const f32x2 P1  = {0.1f, 0.1f};
    const f32x2 P02 = {0.2f, 0.2f};

    // ---- weight frags: direct loads from prep-kernel images (L2-hot)
    int4v BrecHi[2][4], BrecMi[2][4];
#pragma unroll
    for (int t = 0; t < 2; ++t)
#pragma unroll
        for (int kc = 0; kc < 4; ++kc) {
            int set = wv * 8 + t * 4 + kc;
            BrecHi[t][kc] = ws[set * 64 + l];
            BrecMi[t][kc] = ws[2048 + set * 64 + l];
        }
    int4v BwinPk[2];
#pragma unroll
    for (int t = 0; t < 2; ++t)
        BwinPk[t] = ws[4096 + (wv * 2 + t) * 64 + l];
    int4v Bwout[4];
#pragma unroll
    for (int kc = 0; kc < 4; ++kc)
        Bwout[kc] = ws[4608 + kc * 64 + l];

    // ---- encoder: all waves run the register-only ve recurrence
    // (identical ballots); each builds/stores axt frags for its quarter
    // u in [wv*10, wv*10+10). Op chain identical to r17's builder.
    {
        float xv0 = x[(size_t)(b0 + (l >> 3)) * 4 + (l & 3)];
        float xv1 = x[(size_t)(b0 + 8 + (l >> 3)) * 4 + (l & 3)];
        float s0 = 50.0f * xv0, s1 = 50.0f * xv1;
        f32x2 cur, ve = {0.0f, 0.0f};
        cur[0] = (l & 4) ? fmaxf(-s0, 0.0f) : fmaxf(s0, 0.0f);
        cur[1] = (l & 4) ? fmaxf(-s1, 0.0f) : fmaxf(s1, 0.0f);
        const int ulo = wv * 10, uhi = ulo + 10;
#pragma unroll 1
        for (int u = 0; u < TSTEPS; ++u) {
            f32x2 te = cur - ve;            // (0-ve)+cur == cur-ve
            f32x2 vv = ve + P1 * te;
            bool e0 = vv[0] > 1.0f, e1 = vv[1] > 1.0f;
            unsigned long long bm0 = __ballot(e0), bm1 = __ballot(e1);
            ve[0] = e0 ? 0.0f : vv[0];
            ve[1] = e1 ? 0.0f : vv[1];
            if (u >= ulo && u < uhi) {      // wave-uniform branch
                unsigned long long src = (cl < 8) ? (bm0 >> (cl * 8))
                                                  : (bm1 >> ((cl - 8) * 8));
                unsigned byt = (unsigned)src & 0xFFu;
                int4v axt;
                axt[0] = (int)(((byt & 1u)   ? 0x3F80u : 0u) | ((byt & 2u)   ? 0x3F800000u : 0u));
                axt[1] = (int)(((byt & 4u)   ? 0x3F80u : 0u) | ((byt & 8u)   ? 0x3F800000u : 0u));
                axt[2] = (int)(((byt & 16u)  ? 0x3F80u : 0u) | ((byt & 32u)  ? 0x3F800000u : 0u));
                axt[3] = (int)(((byt & 64u)  ? 0x3F80u : 0u) | ((byt & 128u) ? 0x3F800000u : 0u));
                if (l < 32)
                    *reinterpret_cast<int4v*>(&axtlds[u * 512 + l * 16]) = axt;
            }
        }
    }

    // ---- states (C-frag layout: col=lane&15, row=(lane>>4)*4+reg)
    f32x2 iSl[2] = {{0,0},{0,0}}, iSh[2] = {{0,0},{0,0}};
    f32x2 vSl[2] = {{0,0},{0,0}}, vSh[2] = {{0,0},{0,0}};

    // ---- z-tile LDS addresses (byte ^ ((row&7)<<4) swizzle; bit12 = buffer)
    unsigned awrb[2];
#pragma unroll
    for (int t = 0; t < 2; ++t) {
        int col = Ns + t * 16 + cl;
        awrb[t] = (unsigned)((kg * 1024 + col * 2) ^ ((kg & 1) << 6));
    }
    unsigned ard = (unsigned)((cl * 256 + kg * 16) ^ ((cl & 7) << 4)) | 4096u;

    auto loadfrags = [&](int4v* zf) {
#pragma unroll
        for (int kc = 0; kc < 4; ++kc)
            zf[kc] = *reinterpret_cast<int4v*>(&zraw[ard ^ (unsigned)(kc << 6)]);
    };

    // readout MFMA only; cr stored to LDS slot (LI recurrence deferred)
    auto readout_cr = [&](const int4v* zf, int slot) {
        f32x4 cro = {0,0,0,0};
#pragma unroll
        for (int kc = 0; kc < 4; ++kc) cro = mfma16(zf[kc], Bwout[kc], cro);
        f32x4 cr;
#pragma unroll
        for (int r = 0; r < 4; ++r) cr[r] = cro[r] + dpp_mov<0x4E>(cro[r]);
        if (cl < 2) {
#pragma unroll
            for (int r = 0; r < 4; ++r) crlds[slot][kg * 4 + r][cl] = cr[r];
        }
    };

    auto encoder_lif = [&](int u, bool with_rec, const int4v* zf) {
        int4v axt = *reinterpret_cast<const int4v*>(
            &axtlds[u * 512 + (l & 31) * 16]);
#pragma unroll
        for (int t = 0; t < 2; ++t) {
            f32x4 cin = {0,0,0,0};
            cin = mfma16(axt, BwinPk[t], cin);   // hi + mid in one pass
            f32x4 crec = {0,0,0,0};
            if (with_rec) {
#pragma unroll
                for (int kc = 0; kc < 4; ++kc)
                    crec = mfma16(zf[kc], BrecMi[t][kc], crec);
#pragma unroll
                for (int kc = 0; kc < 4; ++kc)
                    crec = mfma16(zf[kc], BrecHi[t][kc], crec);
            }
            // id = i - 0.2*i ; tt = (0-v)+i == i-v ; vd = v + 0.1*tt
            f32x2 idl = iSl[t] - P02 * iSl[t];
            f32x2 idh = iSh[t] - P02 * iSh[t];
            f32x2 ttl = iSl[t] - vSl[t];
            f32x2 tth = iSh[t] - vSh[t];
            f32x2 vdl = vSl[t] + P1 * ttl;
            f32x2 vdh = vSh[t] + P1 * tth;
#pragma unroll
            for (int r = 0; r < 4; ++r) {
                float vdr = (r < 2) ? vdl[r] : vdh[r - 2];
                bool zb = vdr > 1.0f;
                float vres = zb ? 0.0f : vdr;
                if (r == 0)      vSl[t][0] = vres;
                else if (r == 1) vSl[t][1] = vres;
                else if (r == 2) vSh[t][0] = vres;
                else             vSh[t][1] = vres;
                short zv = zb ? (short)0x3F80 : (short)0;
                unsigned a = (awrb[t] ^ (unsigned)(r << 4)) + (unsigned)(r * 256);
                *reinterpret_cast<short*>(&zraw[a]) = zv;
            }
            // iS = (id + cin) + crec    [r11/r15/r17 order]
            iSl[t] = (idl + lo2(cin)) + lo2(crec);
            iSh[t] = (idh + hi2(cin)) + hi2(crec);
        }
    };

    auto toggle = [&]() {
        ard ^= 4096u;
        awrb[0] ^= 4096u;
        awrb[1] ^= 4096u;
    };

    // ---- prologue: axt table visible -> z(0) written -> z(0) visible
    __syncthreads();
    encoder_lif(0, false, nullptr);
    __syncthreads();
    toggle();

#pragma unroll 1
    for (int u = 1; u < TSTEPS; ++u) {
        int4v zf[4];
        loadfrags(zf);                              // z(u-1)
        if (wv == (u & 3)) readout_cr(zf, u - 1);   // cr(u-1), one wave
        encoder_lif(u, true, zf);                   // i/v/z(u)
        __syncthreads();
        toggle();
    }

    // ---- epilogue (wave des): cr(39) from z(39), LI replay, softmax
    if (wv == des) {
        int4v zf[4];
        loadfrags(zf);
        readout_cr(zf, TSTEPS - 1);
        // replay: identical per-element op chain as r15/r17 in-loop LI
        f32x4 io = {0,0,0,0}, vo = {0,0,0,0};
        f32x4 mx = {-3e38f,-3e38f,-3e38f,-3e38f};
        const int ch = cl & 1;
#pragma unroll 1
        for (int u = 0; u < TSTEPS; ++u) {
            f32x4 cr4;
#pragma unroll
            for (int r = 0; r < 4; ++r) cr4[r] = crlds[u][kg * 4 + r][ch];
            f32x4 vn;
#pragma unroll
            for (int r = 0; r < 4; ++r) {
                float t2 = io[r] - vo[r];           // (0-vo)+io == io-vo
                vn[r] = vo[r] + 0.1f * t2;
            }
#pragma unroll
            for (int r = 0; r < 4; ++r)
                io[r] = (io[r] - 0.2f * io[r]) + cr4[r];
            vo = vn;
#pragma unroll
            for (int r = 0; r < 4; ++r) mx[r] = fmaxf(mx[r], vn[r]);
        }
#pragma unroll
        for (int r = 0; r < 4; ++r) {
            float partner = dpp_mov<0xB1>(mx[r]);
            float mm = fmaxf(mx[r], partner);
            float es = expf(mx[r] - mm);
            float ep = expf(partner - mm);
            float inv = 1.0f / (es + ep);
            float pr = es * inv;
            if (cl < 2) out[(size_t)(b0 + kg * 4 + r) * 2 + cl] = pr;
        }
    }
}

extern "C" void kernel_launch(void* const* d_in, const int* in_sizes, int n_in,
                              void* d_out, int out_size, void* d_ws, size_t ws_size,
                              hipStream_t stream) {
    const float* x     = (const float*)d_in[0];
    const float* w_in  = (const float*)d_in[1];
    const float* w_rec = (const float*)d_in[2];
    const float* w_out = (const float*)d_in[3];
    float* out = (float*)d_out;
    int4v* ws = (int4v*)d_ws;

    // frag images: 2816 work items, 16B each output slot (77824 B total)
    prep_kernel<<<11, 256, 0, stream>>>(w_in, w_rec, w_out, ws);

    int B = in_sizes[0] / 4;      // x is (B, 4)
    int blocks = B / 16;          // 16 batch elements per 256-thread block
    snn_kernel<<<blocks, 256, 0, stream>>>(x, ws, out);
}